// Round 4
// baseline (2626.748 us; speedup 1.0000x reference)
//
#include <hip/hip_runtime.h>
#include <hip/hip_bf16.h>
#include <stdint.h>

#define Bn 256
#define Tn 127
#define Kn 128
#define Hn 256

typedef float f32x4 __attribute__((ext_vector_type(4)));
typedef short s16x8 __attribute__((ext_vector_type(8)));

__device__ __forceinline__ float bf2f(unsigned short b){
  union { unsigned u; float f; } v; v.u = ((unsigned)b) << 16; return v.f;
}
__device__ __forceinline__ unsigned short f2bf_rn(float f){
  union { __hip_bfloat16 h; unsigned short s; } u;
  u.h = __float2bfloat16(f);
  return u.s;
}
__device__ __forceinline__ s16x8 cvt8(f32x4 a, f32x4 b){
  union { __hip_bfloat162 h2; unsigned short s[2]; } u0,u1,u2,u3;
  u0.h2 = __float22bfloat162_rn(float2{a[0],a[1]});
  u1.h2 = __float22bfloat162_rn(float2{a[2],a[3]});
  u2.h2 = __float22bfloat162_rn(float2{b[0],b[1]});
  u3.h2 = __float22bfloat162_rn(float2{b[2],b[3]});
  s16x8 r;
  r[0]=(short)u0.s[0]; r[1]=(short)u0.s[1]; r[2]=(short)u1.s[0]; r[3]=(short)u1.s[1];
  r[4]=(short)u2.s[0]; r[5]=(short)u2.s[1]; r[6]=(short)u3.s[0]; r[7]=(short)u3.s[1];
  return r;
}
__device__ __forceinline__ float sigf(float x){ return 1.f/(1.f+__expf(-x)); }
__device__ __forceinline__ float tanh_fast(float x){
  float ax = fabsf(x);
  float e = __expf(-2.f*ax);
  float t = (1.f - e)/(1.f + e);
  return x < 0.f ? -t : t;
}

// ---------------- Phase 0: alpha = softmax(x_score), weight = alpha*input -----
__global__ __launch_bounds__(256) void phase0_kernel(
    const float* __restrict__ in, const float* __restrict__ fc_w,
    float* __restrict__ out)
{
  const int b    = blockIdx.x;
  const int tid  = threadIdx.x;
  const int k    = tid & 127;
  const int half = tid >> 7;
  __shared__ float wx[Tn+1];
  __shared__ float partial[2][128];
  __shared__ float red[8];
  __shared__ float alpha_s[128];
  if (tid < Tn) wx[tid] = fc_w[2*Hn + tid];
  __syncthreads();

  const float* ib = in + (size_t)b*Tn*Kn;
  const int t0 = half*64, t1 = half ? Tn : 64;
  float acc = 0.f;
  for (int t=t0; t<t1; t++) acc += ib[t*Kn + k] * wx[t];
  partial[half][k] = acc;
  __syncthreads();
  const float tot = partial[0][k] + partial[1][k];

  float mx = tot;
#pragma unroll
  for (int o=32;o>0;o>>=1) mx = fmaxf(mx, __shfl_xor(mx, o));
  const int wv = tid >> 6;
  if ((tid & 63) == 0) red[wv] = mx;
  __syncthreads();
  mx = fmaxf(fmaxf(red[0],red[1]), fmaxf(red[2],red[3]));
  float e = __expf(tot - mx);
  float sm = e;
#pragma unroll
  for (int o=32;o>0;o>>=1) sm += __shfl_xor(sm, o);
  if ((tid & 63) == 0) red[4+wv] = sm;
  __syncthreads();
  if (half == 0) alpha_s[k] = e / (red[4] + red[5]);
  __syncthreads();

  // vectorized scale-store: tid -> (t-row tr, float4 col k4)
  const int k4 = tid & 31;
  const int tr = tid >> 5;
  const f32x4 al4 = *(const f32x4*)&alpha_s[k4*4];
  float* ob = out + (size_t)b*Tn*Kn;
  for (int t=tr; t<Tn; t+=8){
    f32x4 v = *(const f32x4*)(ib + t*Kn + k4*4);
    v[0]*=al4[0]; v[1]*=al4[1]; v[2]*=al4[2]; v[3]*=al4[3];
    *(f32x4*)(ob + t*Kn + k4*4) = v;
  }
}

// ---------------- Scan: 32 WGs x 1024 thr; one 8-batch group per WG ----------
// MFMA 16x16x32 bf16. A rows 0-7 = h_hi (batches), rows 8-15 = h_lo; x tiles
// use rows 0-7. D rows m / m+8 are hi/lo partials, combined via shfl_xor(32).
// h lives ONLY in LDS (double buffer); one __syncthreads per step.
// __launch_bounds__(1024, 4): 16-wave WG = 4 waves/SIMD -> VGPR cap 512/wave,
// so the ~290-reg persistent-weight working set stays in registers (R3 bug:
// default bound -> 64 VGPRs -> spill to scratch -> 92 MB WRITE_SIZE).
__global__ __launch_bounds__(1024, 4) void scan_kernel(
    const float* __restrict__ W_ih, const float* __restrict__ W_hh,
    const float* __restrict__ b_ih, const float* __restrict__ b_hh,
    float* __restrict__ out)
{
  const int g    = blockIdx.x;        // 0..31
  const int b0   = g * 8;
  const int tid  = threadIdx.x;
  const int w    = tid >> 6;          // wave 0..15
  const int lane = tid & 63;
  const int c    = lane & 15;
  const int quad = lane >> 4;
  const int u    = w*16 + c;          // hidden unit 0..255

  __shared__ __align__(16) unsigned short hhi[2][8*272];
  __shared__ __align__(16) unsigned short hlo[2][8*272];

  // --- persistent B fragments: 4 gate tiles (i,f,g,o) ---
  s16x8 whh[4][8], wih[4][4];
  float bias[4];
#pragma unroll
  for (int G=0; G<4; G++){
    const int grow = G*Hn + u;
    bias[G] = b_ih[grow] + b_hh[grow];
#pragma unroll
    for (int kb=0; kb<8; kb++){
      const float* p = W_hh + (size_t)grow*Hn + kb*32 + quad*8;
      whh[G][kb] = cvt8(*(const f32x4*)p, *(const f32x4*)(p+4));
    }
#pragma unroll
    for (int kb=0; kb<4; kb++){
      const float* p = W_ih + (size_t)grow*Kn + kb*32 + quad*8;
      wih[G][kb] = cvt8(*(const f32x4*)p, *(const f32x4*)(p+4));
    }
  }

  // epilogue split: quad q handles regs rr=rsel0+rp (rp=0,1), batch m=m0+rp
  const int rsel0 = (quad >> 1) * 2;
  const int prr0  = rsel0 ^ 2;
  const int m0    = (quad & 1)*4 + rsel0;
  float cst[2] = {0.f, 0.f};

  const size_t enc_base = (size_t)Bn*Tn*Kn;
  const float* xrow = out + (size_t)(b0 + (c & 7))*Tn*Kn;

  for (int t=0; t<Tn; t++){
    const int pb = t & 1;

    // ---- x fragment loads (lanes c<8; rows 8-15 stay zero) ----
    f32x4 xa[4], xb[4];
    if (c < 8){
      const float* xp = xrow + (size_t)t*Kn + quad*8;
#pragma unroll
      for (int kb=0; kb<4; kb++){
        xa[kb] = *(const f32x4*)(xp + kb*32);
        xb[kb] = *(const f32x4*)(xp + kb*32 + 4);
      }
    }

    f32x4 acc[4] = {{0.f,0.f,0.f,0.f},{0.f,0.f,0.f,0.f},
                    {0.f,0.f,0.f,0.f},{0.f,0.f,0.f,0.f}};

    // ---- h part: A rows = 8 hi-batches | 8 lo-batches, K=256 ----
    if (t > 0){
      const unsigned short* hb = (c < 8) ? &hhi[pb][c*272] : &hlo[pb][(c-8)*272];
#pragma unroll
      for (int kb=0; kb<8; kb++){
        const s16x8 af = *(const s16x8*)(hb + kb*32 + quad*8);
        acc[0] = __builtin_amdgcn_mfma_f32_16x16x32_bf16(af, whh[0][kb], acc[0],0,0,0);
        acc[1] = __builtin_amdgcn_mfma_f32_16x16x32_bf16(af, whh[1][kb], acc[1],0,0,0);
        acc[2] = __builtin_amdgcn_mfma_f32_16x16x32_bf16(af, whh[2][kb], acc[2],0,0,0);
        acc[3] = __builtin_amdgcn_mfma_f32_16x16x32_bf16(af, whh[3][kb], acc[3],0,0,0);
      }
    }

    // ---- x part: K=128, rows 8-15 = 0 ----
    {
      const s16x8 z = {0,0,0,0,0,0,0,0};
#pragma unroll
      for (int kb=0; kb<4; kb++){
        const s16x8 ax = (c < 8) ? cvt8(xa[kb], xb[kb]) : z;
        acc[0] = __builtin_amdgcn_mfma_f32_16x16x32_bf16(ax, wih[0][kb], acc[0],0,0,0);
        acc[1] = __builtin_amdgcn_mfma_f32_16x16x32_bf16(ax, wih[1][kb], acc[1],0,0,0);
        acc[2] = __builtin_amdgcn_mfma_f32_16x16x32_bf16(ax, wih[2][kb], acc[2],0,0,0);
        acc[3] = __builtin_amdgcn_mfma_f32_16x16x32_bf16(ax, wih[3][kb], acc[3],0,0,0);
      }
    }

    // ---- epilogue: combine hi (rows m) + lo (rows m+8) via shfl_xor(32) ----
#pragma unroll
    for (int rp=0; rp<2; rp++){
      const int rr  = rsel0 + rp;
      const int prr = prr0 + rp;
      const float gi = acc[0][rr] + __shfl_xor(acc[0][prr], 32) + bias[0];
      const float gf = acc[1][rr] + __shfl_xor(acc[1][prr], 32) + bias[1];
      const float gg = acc[2][rr] + __shfl_xor(acc[2][prr], 32) + bias[2];
      const float go = acc[3][rr] + __shfl_xor(acc[3][prr], 32) + bias[3];
      const float cn = sigf(gf)*cst[rp] + sigf(gi)*tanh_fast(gg);
      cst[rp] = cn;
      const float hn = sigf(go)*tanh_fast(cn);

      const int m = m0 + rp;
      const unsigned short hi16 = f2bf_rn(hn);
      const unsigned short lo16 = f2bf_rn(hn - bf2f(hi16));
      hhi[1-pb][m*272 + u] = hi16;
      hlo[1-pb][m*272 + u] = lo16;
      out[enc_base + ((size_t)(b0+m)*Tn + t)*Hn + u] = hn;  // fire-and-forget
    }
    __syncthreads();   // h[1-pb] complete before step t+1 reads it
  }
}

extern "C" void kernel_launch(void* const* d_in, const int* in_sizes, int n_in,
                              void* d_out, int out_size, void* d_ws, size_t ws_size,
                              hipStream_t stream) {
  const float* input = (const float*)d_in[0];
  const float* W_ih  = (const float*)d_in[1];
  const float* W_hh  = (const float*)d_in[2];
  const float* b_ih  = (const float*)d_in[3];
  const float* b_hh  = (const float*)d_in[4];
  const float* fc_w  = (const float*)d_in[5];
  float* out = (float*)d_out;

  phase0_kernel<<<Bn, 256, 0, stream>>>(input, fc_w, out);
  scan_kernel<<<32, 1024, 0, stream>>>(W_ih, W_hh, b_ih, b_hh, out);
}

// Round 5
// 608.017 us; speedup vs baseline: 4.3202x; 4.3202x over previous
//
#include <hip/hip_runtime.h>
#include <hip/hip_bf16.h>
#include <stdint.h>

#define Bn 256
#define Tn 127
#define Kn 128
#define Hn 256

typedef float f32x4 __attribute__((ext_vector_type(4)));
typedef short s16x8 __attribute__((ext_vector_type(8)));

// ws layout
#define GX_BYTES   66584576ULL   // bf16 [32][127][2][8][4][128]
#define BAR_OFF    66584576ULL   // uint [64][32] (flag per (g,s), 128B apart)
#define REC_OFF    66592768ULL   // ull  [32][2][2 parity][512]

__device__ __forceinline__ float bf2f(unsigned short b){
  union { unsigned u; float f; } v; v.u = ((unsigned)b) << 16; return v.f;
}
__device__ __forceinline__ unsigned short f2bf_rn(float f){
  union { __hip_bfloat16 h; unsigned short s; } u;
  u.h = __float2bfloat16(f);
  return u.s;
}
__device__ __forceinline__ s16x8 cvt8(f32x4 a, f32x4 b){
  union { __hip_bfloat162 h2; unsigned short s[2]; } u0,u1,u2,u3;
  u0.h2 = __float22bfloat162_rn(float2{a[0],a[1]});
  u1.h2 = __float22bfloat162_rn(float2{a[2],a[3]});
  u2.h2 = __float22bfloat162_rn(float2{b[0],b[1]});
  u3.h2 = __float22bfloat162_rn(float2{b[2],b[3]});
  s16x8 r;
  r[0]=(short)u0.s[0]; r[1]=(short)u0.s[1]; r[2]=(short)u1.s[0]; r[3]=(short)u1.s[1];
  r[4]=(short)u2.s[0]; r[5]=(short)u2.s[1]; r[6]=(short)u3.s[0]; r[7]=(short)u3.s[1];
  return r;
}
__device__ __forceinline__ float sigf(float x){ return 1.f/(1.f+__expf(-x)); }
__device__ __forceinline__ float tanh_fast(float x){
  float ax = fabsf(x);
  float e = __expf(-2.f*ax);
  float t = (1.f - e)/(1.f + e);
  return x < 0.f ? -t : t;
}

// ---------------- Phase 0: alpha = softmax(x_score), weight = alpha*input -----
__global__ __launch_bounds__(256) void phase0_kernel(
    const float* __restrict__ in, const float* __restrict__ fc_w,
    float* __restrict__ out)
{
  const int b    = blockIdx.x;
  const int tid  = threadIdx.x;
  const int k    = tid & 127;
  const int half = tid >> 7;
  __shared__ float wx[Tn+1];
  __shared__ float partial[2][128];
  __shared__ float red[8];
  __shared__ float alpha_s[128];
  if (tid < Tn) wx[tid] = fc_w[2*Hn + tid];
  __syncthreads();

  const float* ib = in + (size_t)b*Tn*Kn;
  const int t0 = half*64, t1 = half ? Tn : 64;
  float acc = 0.f;
  for (int t=t0; t<t1; t++) acc += ib[t*Kn + k] * wx[t];
  partial[half][k] = acc;
  __syncthreads();
  const float tot = partial[0][k] + partial[1][k];

  float mx = tot;
#pragma unroll
  for (int o=32;o>0;o>>=1) mx = fmaxf(mx, __shfl_xor(mx, o));
  const int wv = tid >> 6;
  if ((tid & 63) == 0) red[wv] = mx;
  __syncthreads();
  mx = fmaxf(fmaxf(red[0],red[1]), fmaxf(red[2],red[3]));
  float e = __expf(tot - mx);
  float sm = e;
#pragma unroll
  for (int o=32;o>0;o>>=1) sm += __shfl_xor(sm, o);
  if ((tid & 63) == 0) red[4+wv] = sm;
  __syncthreads();
  if (half == 0) alpha_s[k] = e / (red[4] + red[5]);
  __syncthreads();

  const int k4 = tid & 31;
  const int tr = tid >> 5;
  const f32x4 al4 = *(const f32x4*)&alpha_s[k4*4];
  float* ob = out + (size_t)b*Tn*Kn;
  for (int t=tr; t<Tn; t+=8){
    f32x4 v = *(const f32x4*)(ib + t*Kn + k4*4);
    v[0]*=al4[0]; v[1]*=al4[1]; v[2]*=al4[2]; v[3]*=al4[3];
    *(f32x4*)(ob + t*Kn + k4*4) = v;
  }
}

// ---------------- Phase GX: gx = x @ W_ih^T + bias, packed in MFMA C-layout --
// Grid 2048 = 32 groups x 64 t-pairs; 256 thr (4 waves). A-tile rows =
// (2 t) x (8 batches); each wave covers 16 of the 64 N-tiles.
__global__ __launch_bounds__(256) void gx_kernel(
    const float* __restrict__ xw, const float* __restrict__ W_ih,
    const float* __restrict__ b_ih, const float* __restrict__ b_hh,
    __hip_bfloat16* __restrict__ gx)
{
  const int g    = blockIdx.x & 31;
  const int tp   = blockIdx.x >> 5;       // 0..63
  const int t0   = tp*2;
  const int tid  = threadIdx.x;
  const int wv   = tid >> 6;
  const int lane = tid & 63;
  const int c    = lane & 15;
  const int quad = lane >> 4;

  // A fragments: row c -> (t = t0 + c/8, b = g*8 + c%8)
  const int b  = g*8 + (c & 7);
  const int tt = min(t0 + (c >> 3), Tn-1);
  s16x8 afr[4];
  const float* xp = xw + ((size_t)b*Tn + tt)*Kn + quad*8;
#pragma unroll
  for (int kb=0; kb<4; kb++)
    afr[kb] = cvt8(*(const f32x4*)(xp + kb*32), *(const f32x4*)(xp + kb*32 + 4));

  const int trow = t0 + (quad >> 1);
  const int mh   = (quad & 1) * 4;

  for (int j = wv*16; j < wv*16+16; j++){
    const int n = j*16 + c;
    const float bias = b_ih[n] + b_hh[n];
    f32x4 acc = {bias, bias, bias, bias};
    const float* wp = W_ih + (size_t)n*Kn + quad*8;
#pragma unroll
    for (int kb=0; kb<4; kb++){
      const s16x8 bfr = cvt8(*(const f32x4*)(wp + kb*32), *(const f32x4*)(wp + kb*32 + 4));
      acc = __builtin_amdgcn_mfma_f32_16x16x32_bf16(afr[kb], bfr, acc, 0,0,0);
    }
    if (trow < Tn){
      const int G = j >> 4, rem = j & 15, s = rem >> 3, w8 = rem & 7;
      __hip_bfloat16* dst = gx +
        (((((size_t)g*Tn + trow)*2 + s)*8 + w8)*4 + G)*128 + c*8 + mh;
      ushort4 pk;
      pk.x = f2bf_rn(acc[0]); pk.y = f2bf_rn(acc[1]);
      pk.z = f2bf_rn(acc[2]); pk.w = f2bf_rn(acc[3]);
      *(ushort4*)dst = pk;
    }
  }
}

// ---------------- Scan: 32 groups x 2 N-slices, W_hh-only in registers ------
__global__ __launch_bounds__(512, 2) void scan_kernel(
    const float* __restrict__ W_hh, float* __restrict__ out,
    const __hip_bfloat16* __restrict__ gx,
    unsigned* __restrict__ bar, unsigned long long* __restrict__ rec)
{
  const int bid  = blockIdx.x;
  const int s    = (bid >> 3) & 1;                  // slice
  const int g    = (bid & 7) | ((bid >> 4) << 3);   // group; pair shares bid%8
  const int b0   = g * 8;
  const int tid  = threadIdx.x;
  const int w    = tid >> 6;          // wave 0..7 (unit-group)
  const int lane = tid & 63;
  const int c    = lane & 15;
  const int quad = lane >> 4;
  const int u    = s*128 + w*16 + c;  // global hidden unit

  __shared__ __align__(16) unsigned short hhi[2*8*272];
  __shared__ __align__(16) unsigned short hlo[2*8*272];

  // persistent W_hh B-frags: 4 gates x 8 kb = 128 VGPRs
  s16x8 whh[4][8];
#pragma unroll
  for (int G=0; G<4; G++){
    const float* p0 = W_hh + (size_t)(G*Hn + u)*Hn + quad*8;
#pragma unroll
    for (int kb=0; kb<8; kb++)
      whh[G][kb] = cvt8(*(const f32x4*)(p0 + kb*32), *(const f32x4*)(p0 + kb*32 + 4));
  }

  const int rsel0 = (quad >> 1) * 2;
  const int prr0  = rsel0 ^ 2;
  const int m0    = (quad & 1)*4 + rsel0;
  float cst[2] = {0.f, 0.f};

  const size_t enc_base = (size_t)Bn*Tn*Kn;
  unsigned* flag_mine  = bar + ((size_t)g*2 + s)*32;
  unsigned* flag_other = bar + ((size_t)g*2 + (1-s))*32;
  unsigned long long* rec_mine  = rec + (((size_t)g*2 + s)*2)*512;
  unsigned long long* rec_other = rec + (((size_t)g*2 + (1-s))*2)*512;

  // remote-fill decode for lane index tid (matches producer packing)
  const int rw   = tid >> 6, rl = tid & 63;
  const int rc   = rl & 15,  rq = rl >> 4;
  const int r_m0 = (rq & 1)*4 + (rq >> 1)*2;
  const int r_u  = rw*16 + rc;                 // remote-local unit 0..127
  const int rk   = (1-s)*128 + r_u;            // K-column in LDS

  const __hip_bfloat16* gxg = gx + ((((size_t)g*Tn)*2 + s)*8 + w)*4*128;

  for (int t=0; t<Tn; t++){
    const int buf = (t & 1) * 8*272;

    // ---- gx prefetch (C-layout; rows 0-7 only -> quad<2) ----
    ushort4 gxr[4];
    if (quad < 2){
      const __hip_bfloat16* gp = gxg + (size_t)t*2*8*4*128 + c*8 + quad*4;
#pragma unroll
      for (int G=0; G<4; G++) gxr[G] = *(const ushort4*)(gp + G*128);
    }

    if (t > 0){
      // ---- wait for partner's step t-1, then fill remote half of LDS ----
      if (lane == 0){
        const unsigned tgt = 8u * (unsigned)t;
        while (__hip_atomic_load(flag_other, __ATOMIC_RELAXED, __HIP_MEMORY_SCOPE_AGENT) < tgt)
          __builtin_amdgcn_s_sleep(1);
      }
      asm volatile("" ::: "memory");
      union { unsigned long long q; unsigned short h[4]; } rv;
      rv.q = __hip_atomic_load(rec_other + ((size_t)((t-1)&1))*512 + tid,
                               __ATOMIC_RELAXED, __HIP_MEMORY_SCOPE_AGENT);
      hhi[buf + r_m0*272 + rk]     = rv.h[0];
      hlo[buf + r_m0*272 + rk]     = rv.h[1];
      hhi[buf + (r_m0+1)*272 + rk] = rv.h[2];
      hlo[buf + (r_m0+1)*272 + rk] = rv.h[3];
      __syncthreads();
    }

    // ---- acc init from gx (hi rows) ----
    f32x4 acc[4];
#pragma unroll
    for (int G=0; G<4; G++){
      if (quad < 2){
        acc[G][0]=bf2f(gxr[G].x); acc[G][1]=bf2f(gxr[G].y);
        acc[G][2]=bf2f(gxr[G].z); acc[G][3]=bf2f(gxr[G].w);
      } else {
        acc[G][0]=0.f; acc[G][1]=0.f; acc[G][2]=0.f; acc[G][3]=0.f;
      }
    }

    // ---- h MFMA: A rows = 8 hi | 8 lo batches, K=256 ----
    if (t > 0){
      const unsigned short* hb = (c < 8) ? &hhi[buf + c*272] : &hlo[buf + (c-8)*272];
#pragma unroll
      for (int kb=0; kb<8; kb++){
        const s16x8 af = *(const s16x8*)(hb + kb*32 + quad*8);
        acc[0] = __builtin_amdgcn_mfma_f32_16x16x32_bf16(af, whh[0][kb], acc[0],0,0,0);
        acc[1] = __builtin_amdgcn_mfma_f32_16x16x32_bf16(af, whh[1][kb], acc[1],0,0,0);
        acc[2] = __builtin_amdgcn_mfma_f32_16x16x32_bf16(af, whh[2][kb], acc[2],0,0,0);
        acc[3] = __builtin_amdgcn_mfma_f32_16x16x32_bf16(af, whh[3][kb], acc[3],0,0,0);
      }
    }

    // ---- epilogue: combine hi/lo via shfl_xor(32); 2 LSTM updates/lane ----
    const int nbuf = ((t+1) & 1) * 8*272;
    float hv[2];
#pragma unroll
    for (int rp=0; rp<2; rp++){
      const int rr  = rsel0 + rp;
      const int prr = prr0 + rp;
      const float gi = acc[0][rr] + __shfl_xor(acc[0][prr], 32);
      const float gf = acc[1][rr] + __shfl_xor(acc[1][prr], 32);
      const float gg = acc[2][rr] + __shfl_xor(acc[2][prr], 32);
      const float go = acc[3][rr] + __shfl_xor(acc[3][prr], 32);
      const float cn = sigf(gf)*cst[rp] + sigf(gi)*tanh_fast(gg);
      cst[rp] = cn;
      hv[rp] = sigf(go)*tanh_fast(cn);
    }

    // ---- publish record first (short flag path) ----
    union { unsigned long long q; unsigned short h[4]; } pk;
    const unsigned short hi0 = f2bf_rn(hv[0]);
    const unsigned short hi1 = f2bf_rn(hv[1]);
    pk.h[0] = hi0; pk.h[1] = f2bf_rn(hv[0] - bf2f(hi0));
    pk.h[2] = hi1; pk.h[3] = f2bf_rn(hv[1] - bf2f(hi1));
    if (t < Tn-1){
      __hip_atomic_store(rec_mine + ((size_t)(t&1))*512 + tid, pk.q,
                         __ATOMIC_RELAXED, __HIP_MEMORY_SCOPE_AGENT);
      asm volatile("s_waitcnt vmcnt(0)" ::: "memory");
      if (lane == 0)
        __hip_atomic_fetch_add(flag_mine, 1u, __ATOMIC_RELAXED, __HIP_MEMORY_SCOPE_AGENT);
    }

    // ---- own half of next step's LDS + encode output ----
#pragma unroll
    for (int rp=0; rp<2; rp++){
      const int m = m0 + rp;
      hhi[nbuf + m*272 + u] = pk.h[2*rp];
      hlo[nbuf + m*272 + u] = pk.h[2*rp+1];
      out[enc_base + ((size_t)(b0+m)*Tn + t)*Hn + u] = hv[rp];
    }
    __syncthreads();
  }
}

extern "C" void kernel_launch(void* const* d_in, const int* in_sizes, int n_in,
                              void* d_out, int out_size, void* d_ws, size_t ws_size,
                              hipStream_t stream) {
  const float* input = (const float*)d_in[0];
  const float* W_ih  = (const float*)d_in[1];
  const float* W_hh  = (const float*)d_in[2];
  const float* b_ih  = (const float*)d_in[3];
  const float* b_hh  = (const float*)d_in[4];
  const float* fc_w  = (const float*)d_in[5];
  float* out = (float*)d_out;

  char* wsb = (char*)d_ws;
  __hip_bfloat16* gxp = (__hip_bfloat16*)wsb;
  unsigned* bar = (unsigned*)(wsb + BAR_OFF);
  unsigned long long* rec = (unsigned long long*)(wsb + REC_OFF);

  hipMemsetAsync(bar, 0, 8192, stream);
  phase0_kernel<<<Bn, 256, 0, stream>>>(input, fc_w, out);
  gx_kernel<<<2048, 256, 0, stream>>>(out, W_ih, b_ih, b_hh, gxp);
  scan_kernel<<<64, 512, 0, stream>>>(W_hh, out, gxp, bar, rec);
}